// Round 11
// baseline (129.235 us; speedup 1.0000x reference)
//
#include <hip/hip_runtime.h>

// SAXS loss: soft-binned pair-distance histograms for pred & true structures,
// normalized, then L1-summed. N = 256*37 = 9472 atoms = 37 tiles of 256 exactly.
// Symmetry: count i<j only (doubling cancels in normalization).
//
// R10 -> R11: R7-R10 all issue the same 1.44M wave-level ds_add_u32 and all
// land at ~32 cyc/instr => LDS atomic unit ~2 lane-updates/cyc/CU is the
// floor (92.1M updates -> 75 us). This round removes the only free updates:
// (1) diagonal tiles get a wave-uniform loop bound (38% of diag iterations
// have the whole wave failing i<j -> skip the instructions entirely);
// (2) diag-only `if (tot)` guard masks inactive lanes -> probes whether the
// atomic unit charges active lanes or whole instructions.
// Everything else identical to R10 (SMEM i-atom loads, packed fp32 chains,
// q8 dual-array packing, one ds_add_u32 per pair, NREP16, grid (703,2)).

#define TILE    256
#define NTILES  37                            // 9472 / 256, exact
#define TPAIRS  (NTILES * (NTILES + 1) / 2)   // 703 triangular tile pairs
#define NBINS   201
#define NREP    16                            // LDS replicas per structure
#define RSTRIDE 201                           // u32 words per replica
#define SOFF    (NREP * RSTRIDE)              // LDS offset of true-structure hists
#define HSTRIDE 256                           // per-structure u64 hist stride in ws

typedef float v2f __attribute__((ext_vector_type(2)));

template<bool DIAG>
__device__ __forceinline__ void accum_tile(
    const float* __restrict__ posP, const float* __restrict__ posT,
    const float* __restrict__ mask,
    int i0,                                    // uniform global first i-atom
    int iLoc0,                                 // tile-local first i (DIAG test)
    int t,
    v2f xj, v2f yj, v2f zj, unsigned vj,
    unsigned int* __restrict__ repP, unsigned int* __restrict__ repT)
{
    // DIAG: iteration iLoc = iLoc0+i is useful only if some lane has
    // iLoc < j_local; wave w covers j_local in [64w, 64w+64) -> skip all
    // iterations with iLoc0+i >= 64w+63 (wave-uniform bound, no branches).
    int iMax = 128;
    if (DIAG) {
        const int w = t >> 6;
        const int lim = 64 * w + 63 - iLoc0;
        iMax = lim < 0 ? 0 : (lim > 128 ? 128 : lim);
    }

    #pragma unroll 4
    for (int i = 0; i < iMax; ++i) {
        const int ig = i0 + i;                 // uniform -> s_load path
        const float sxp = posP[3 * ig];
        const float syp = posP[3 * ig + 1];
        const float szp = posP[3 * ig + 2];
        const float sxt = posT[3 * ig];
        const float syt = posT[3 * ig + 1];
        const float szt = posT[3 * ig + 2];
        // uniform mask -> SALU compare/select (q8 weight 0 or 256)
        const unsigned ms = (mask[ig] != 0.0f) ? 256u : 0u;

        unsigned tot = ms & vj;                // vj per-lane 0 / ~0
        if (DIAG) tot = (iLoc0 + i < t) ? tot : 0u;   // i<j on diagonal tile
        const float wpf = (float)tot;

        // packed pred/true distance chains (v_pk_sub / v_pk_fma)
        const v2f dx = (v2f){sxp, sxt} - xj;
        const v2f dy = (v2f){syp, syt} - yj;
        const v2f dz = (v2f){szp, szt} - zj;
        v2f d2 = dx * dx;
        d2 = dy * dy + d2;
        d2 = dz * dz + d2;
        d2 = d2 * 4.0f;                        // t = d/0.5 -> sqrt(4*d2)

        // pred chain
        const float ttp = fminf(__builtin_amdgcn_sqrtf(d2.x), 200.0f);
        const unsigned lop = (unsigned)ttp;
        const unsigned qp  = (unsigned)fmaf(wpf, __builtin_amdgcn_fractf(ttp), 0.5f);
        // true chain (independent -> ILP)
        const float ttt = fminf(__builtin_amdgcn_sqrtf(d2.y), 200.0f);
        const unsigned lot = (unsigned)ttt;
        const unsigned qt  = (unsigned)fmaf(wpf, __builtin_amdgcn_fractf(ttt), 0.5f);

        if (!DIAG || tot != 0u) {              // diag: mask inactive lanes
            atomicAdd(&repP[lop], (qp << 16) + (tot - qp));      // ds_add_u32
            atomicAdd(&repT[lot], (qt << 16) + (tot - qt));      // ds_add_u32
        }
    }
}

__global__ __launch_bounds__(TILE) void saxs_hist_kernel(
    const float* __restrict__ posPred,
    const float* __restrict__ posTrue,
    const float* __restrict__ mask,
    unsigned long long* __restrict__ gh,
    unsigned int* __restrict__ counter,
    float* __restrict__ out)
{
    const int t = threadIdx.x;

    // Decode triangular tile index -> (a, b), a <= b. Wave-uniform, once.
    int p = blockIdx.x;
    int a = 0;
    while (p >= NTILES - a) { p -= NTILES - a; ++a; }
    const int b = a + p;

    __shared__ unsigned int sHist[2 * NREP * RSTRIDE];   // 25728 B -> 6 blocks/CU
    {   // vectorized zero-init (6432 u32 = 1608 uint4)
        uint4* s4 = (uint4*)sHist;
        for (int k = t; k < (2 * NREP * RSTRIDE) / 4; k += TILE)
            s4[k] = make_uint4(0u, 0u, 0u, 0u);
    }

    // j-atom (one per thread) from tile b, both structures (raw coords).
    const int jg = b * TILE + t;
    const v2f xj = (v2f){posPred[3 * jg],     posTrue[3 * jg]};
    const v2f yj = (v2f){posPred[3 * jg + 1], posTrue[3 * jg + 1]};
    const v2f zj = (v2f){posPred[3 * jg + 2], posTrue[3 * jg + 2]};
    const unsigned vj = (mask[jg] != 0.0f) ? 0xFFFFFFFFu : 0u;

    __syncthreads();

    unsigned int* __restrict__ repP = sHist + (t & (NREP - 1)) * RSTRIDE;
    unsigned int* __restrict__ repT = repP + SOFF;

    // This block handles 128 i-atoms: tile-local [128*by, 128*by+128).
    const int iLoc0 = 128 * blockIdx.y;
    const int i0 = __builtin_amdgcn_readfirstlane(a * TILE + iLoc0);

    if (a != b) accum_tile<false>(posPred, posTrue, mask, i0, iLoc0, t,
                                  xj, yj, zj, vj, repP, repT);
    else        accum_tile<true >(posPred, posTrue, mask, i0, iLoc0, t,
                                  xj, yj, zj, vj, repP, repT);

    __syncthreads();

    // Reduce replicas: bin k = sum_r low16(W[r][k]) + high16(W[r][k-1]);
    // both structures (402 bins total), one global u64 add per bin per block.
    for (int k = t; k < 2 * NBINS; k += TILE) {
        const int s  = (k < NBINS) ? 0 : 1;
        const int kk = k - s * NBINS;
        const unsigned int* h = sHist + s * SOFF;
        unsigned int acc = 0;
        #pragma unroll
        for (int r = 0; r < NREP; ++r) {
            acc += h[r * RSTRIDE + kk] & 0xFFFFu;
            if (kk > 0) acc += h[r * RSTRIDE + kk - 1] >> 16;
        }
        atomicAdd(&gh[s * HSTRIDE + kk], (unsigned long long)acc);
    }

    // ---- fused loss: last block to finish computes the L1 of normalized hists
    __syncthreads();
    __shared__ int sLast;
    if (t == 0) {
        __threadfence();                   // publish our adds (device scope)
        const unsigned prev = __hip_atomic_fetch_add(
            counter, 1u, __ATOMIC_ACQ_REL, __HIP_MEMORY_SCOPE_AGENT);
        sLast = (prev == 2u * TPAIRS - 1u);
    }
    __syncthreads();
    if (sLast && t < 64) {
        const int ln = t;                  // single wave of 64
        float hp[4], ht[4];
        float sp = 0.0f, st = 0.0f;
        #pragma unroll
        for (int r = 0; r < 4; ++r) {
            const int k = ln + 64 * r;
            float av = 0.0f, cv = 0.0f;
            if (k < NBINS) {
                av = (float)__hip_atomic_load(&gh[k],           __ATOMIC_RELAXED,
                                              __HIP_MEMORY_SCOPE_AGENT);
                cv = (float)__hip_atomic_load(&gh[HSTRIDE + k], __ATOMIC_RELAXED,
                                              __HIP_MEMORY_SCOPE_AGENT);
            }
            hp[r] = av; ht[r] = cv;
            sp += av; st += cv;
        }
        #pragma unroll
        for (int off = 32; off > 0; off >>= 1) {
            sp += __shfl_xor(sp, off);
            st += __shfl_xor(st, off);
        }
        sp += 1e-12f;
        st += 1e-12f;
        float l = 0.0f;
        #pragma unroll
        for (int r = 0; r < 4; ++r) l += fabsf(hp[r] / sp - ht[r] / st);
        #pragma unroll
        for (int off = 32; off > 0; off >>= 1) l += __shfl_xor(l, off);
        if (ln == 0) out[0] = l;
    }
}

extern "C" void kernel_launch(void* const* d_in, const int* in_sizes, int n_in,
                              void* d_out, int out_size, void* d_ws, size_t ws_size,
                              hipStream_t stream)
{
    const float* pred = (const float*)d_in[0];  // final_atom_positions [256,37,3]
    const float* tru  = (const float*)d_in[1];  // all_atom_positions   [256,37,3]
    const float* msk  = (const float*)d_in[2];  // all_atom_mask        [256,37]
    float* out = (float*)d_out;
    unsigned long long* ws = (unsigned long long*)d_ws;
    unsigned int* counter = (unsigned int*)(ws + 2 * HSTRIDE);

    // ws is poisoned 0xAA before every timed launch — zero hists + counter.
    hipMemsetAsync(d_ws, 0, (2 * HSTRIDE + 1) * sizeof(unsigned long long), stream);

    saxs_hist_kernel<<<dim3(TPAIRS, 2), dim3(TILE), 0, stream>>>(
        pred, tru, msk, ws, counter, out);
}

// Round 12
// 126.799 us; speedup vs baseline: 1.0192x; 1.0192x over previous
//
#include <hip/hip_runtime.h>

// SAXS loss: soft-binned pair-distance histograms for pred & true structures,
// normalized, then L1-summed. N = 256*37 = 9472 atoms = 37 tiles of 256 exactly.
// Symmetry: count i<j only (doubling cancels in normalization).
//
// FINAL (R12 = R10 reverted): the kernel is LDS-atomic-throughput bound.
// Evidence (R7-R11): five structurally different kernels all issue 1.44M
// wave-level ds_add_u32 and all land at ~32 cyc/instr (2 lane-updates/cyc/CU)
// invariant to banking (NREP 16/32), occupancy (22-38%), VALU load
// (134k->84k cyc/SIMD), and active-lane masking (R11 probe) => per-
// instruction pipe cost. Floor: 92.1M updates -> 75 us; this kernel runs
// ~76 us (=101% of ceiling). Lane packing is optimal (1 update/lane-slot).
// Structure: fused pred+true pass, SMEM s_load i-atoms (wave-uniform),
// packed-fp32 (v_pk) distance chains, q8 weights packed in u16 fields of
// one ds_add_u32 per pair per structure, 16 LDS replicas/structure
// (25.7 KB -> 6 blocks/CU), grid (703,2) with 128 i-atoms per block,
// last-block-done fused loss reduction.

#define TILE    256
#define NTILES  37                            // 9472 / 256, exact
#define TPAIRS  (NTILES * (NTILES + 1) / 2)   // 703 triangular tile pairs
#define NBINS   201
#define NREP    16                            // LDS replicas per structure
#define RSTRIDE 201                           // u32 words per replica
#define SOFF    (NREP * RSTRIDE)              // LDS offset of true-structure hists
#define HSTRIDE 256                           // per-structure u64 hist stride in ws

typedef float v2f __attribute__((ext_vector_type(2)));

template<bool DIAG>
__device__ __forceinline__ void accum_tile(
    const float* __restrict__ posP, const float* __restrict__ posT,
    const float* __restrict__ mask,
    int i0,                                    // uniform global first i-atom
    int iLoc0,                                 // tile-local first i (DIAG test)
    int t,
    v2f xj, v2f yj, v2f zj, unsigned vj,
    unsigned int* __restrict__ repP, unsigned int* __restrict__ repT)
{
    #pragma unroll 8
    for (int i = 0; i < 128; ++i) {
        const int ig = i0 + i;                 // uniform -> s_load path
        const float sxp = posP[3 * ig];
        const float syp = posP[3 * ig + 1];
        const float szp = posP[3 * ig + 2];
        const float sxt = posT[3 * ig];
        const float syt = posT[3 * ig + 1];
        const float szt = posT[3 * ig + 2];
        // uniform mask -> SALU compare/select (q8 weight 0 or 256)
        const unsigned ms = (mask[ig] != 0.0f) ? 256u : 0u;

        unsigned tot = ms & vj;                // vj per-lane 0 / ~0
        if (DIAG) tot = (iLoc0 + i < t) ? tot : 0u;   // i<j on diagonal tile
        const float wpf = (float)tot;

        // packed pred/true distance chains (v_pk_sub / v_pk_fma)
        const v2f dx = (v2f){sxp, sxt} - xj;
        const v2f dy = (v2f){syp, syt} - yj;
        const v2f dz = (v2f){szp, szt} - zj;
        v2f d2 = dx * dx;
        d2 = dy * dy + d2;
        d2 = dz * dz + d2;
        d2 = d2 * 4.0f;                        // t = d/0.5 -> sqrt(4*d2)

        // pred chain
        const float ttp = fminf(__builtin_amdgcn_sqrtf(d2.x), 200.0f);
        const unsigned lop = (unsigned)ttp;
        const unsigned qp  = (unsigned)fmaf(wpf, __builtin_amdgcn_fractf(ttp), 0.5f);
        atomicAdd(&repP[lop], (qp << 16) + (tot - qp));      // ds_add_u32

        // true chain (independent -> ILP)
        const float ttt = fminf(__builtin_amdgcn_sqrtf(d2.y), 200.0f);
        const unsigned lot = (unsigned)ttt;
        const unsigned qt  = (unsigned)fmaf(wpf, __builtin_amdgcn_fractf(ttt), 0.5f);
        atomicAdd(&repT[lot], (qt << 16) + (tot - qt));      // ds_add_u32
    }
}

__global__ __launch_bounds__(TILE) void saxs_hist_kernel(
    const float* __restrict__ posPred,
    const float* __restrict__ posTrue,
    const float* __restrict__ mask,
    unsigned long long* __restrict__ gh,
    unsigned int* __restrict__ counter,
    float* __restrict__ out)
{
    const int t = threadIdx.x;

    // Decode triangular tile index -> (a, b), a <= b. Wave-uniform, once.
    int p = blockIdx.x;
    int a = 0;
    while (p >= NTILES - a) { p -= NTILES - a; ++a; }
    const int b = a + p;

    __shared__ unsigned int sHist[2 * NREP * RSTRIDE];   // 25728 B -> 6 blocks/CU
    {   // vectorized zero-init (6432 u32 = 1608 uint4)
        uint4* s4 = (uint4*)sHist;
        for (int k = t; k < (2 * NREP * RSTRIDE) / 4; k += TILE)
            s4[k] = make_uint4(0u, 0u, 0u, 0u);
    }

    // j-atom (one per thread) from tile b, both structures (raw coords).
    const int jg = b * TILE + t;
    const v2f xj = (v2f){posPred[3 * jg],     posTrue[3 * jg]};
    const v2f yj = (v2f){posPred[3 * jg + 1], posTrue[3 * jg + 1]};
    const v2f zj = (v2f){posPred[3 * jg + 2], posTrue[3 * jg + 2]};
    const unsigned vj = (mask[jg] != 0.0f) ? 0xFFFFFFFFu : 0u;

    __syncthreads();

    unsigned int* __restrict__ repP = sHist + (t & (NREP - 1)) * RSTRIDE;
    unsigned int* __restrict__ repT = repP + SOFF;

    // This block handles 128 i-atoms: tile-local [128*by, 128*by+128).
    const int iLoc0 = 128 * blockIdx.y;
    const int i0 = __builtin_amdgcn_readfirstlane(a * TILE + iLoc0);

    if (a != b) accum_tile<false>(posPred, posTrue, mask, i0, iLoc0, t,
                                  xj, yj, zj, vj, repP, repT);
    else        accum_tile<true >(posPred, posTrue, mask, i0, iLoc0, t,
                                  xj, yj, zj, vj, repP, repT);

    __syncthreads();

    // Reduce replicas: bin k = sum_r low16(W[r][k]) + high16(W[r][k-1]);
    // both structures (402 bins total), one global u64 add per bin per block.
    for (int k = t; k < 2 * NBINS; k += TILE) {
        const int s  = (k < NBINS) ? 0 : 1;
        const int kk = k - s * NBINS;
        const unsigned int* h = sHist + s * SOFF;
        unsigned int acc = 0;
        #pragma unroll
        for (int r = 0; r < NREP; ++r) {
            acc += h[r * RSTRIDE + kk] & 0xFFFFu;
            if (kk > 0) acc += h[r * RSTRIDE + kk - 1] >> 16;
        }
        atomicAdd(&gh[s * HSTRIDE + kk], (unsigned long long)acc);
    }

    // ---- fused loss: last block to finish computes the L1 of normalized hists
    __syncthreads();
    __shared__ int sLast;
    if (t == 0) {
        __threadfence();                   // publish our adds (device scope)
        const unsigned prev = __hip_atomic_fetch_add(
            counter, 1u, __ATOMIC_ACQ_REL, __HIP_MEMORY_SCOPE_AGENT);
        sLast = (prev == 2u * TPAIRS - 1u);
    }
    __syncthreads();
    if (sLast && t < 64) {
        const int ln = t;                  // single wave of 64
        float hp[4], ht[4];
        float sp = 0.0f, st = 0.0f;
        #pragma unroll
        for (int r = 0; r < 4; ++r) {
            const int k = ln + 64 * r;
            float av = 0.0f, cv = 0.0f;
            if (k < NBINS) {
                av = (float)__hip_atomic_load(&gh[k],           __ATOMIC_RELAXED,
                                              __HIP_MEMORY_SCOPE_AGENT);
                cv = (float)__hip_atomic_load(&gh[HSTRIDE + k], __ATOMIC_RELAXED,
                                              __HIP_MEMORY_SCOPE_AGENT);
            }
            hp[r] = av; ht[r] = cv;
            sp += av; st += cv;
        }
        #pragma unroll
        for (int off = 32; off > 0; off >>= 1) {
            sp += __shfl_xor(sp, off);
            st += __shfl_xor(st, off);
        }
        sp += 1e-12f;
        st += 1e-12f;
        float l = 0.0f;
        #pragma unroll
        for (int r = 0; r < 4; ++r) l += fabsf(hp[r] / sp - ht[r] / st);
        #pragma unroll
        for (int off = 32; off > 0; off >>= 1) l += __shfl_xor(l, off);
        if (ln == 0) out[0] = l;
    }
}

extern "C" void kernel_launch(void* const* d_in, const int* in_sizes, int n_in,
                              void* d_out, int out_size, void* d_ws, size_t ws_size,
                              hipStream_t stream)
{
    const float* pred = (const float*)d_in[0];  // final_atom_positions [256,37,3]
    const float* tru  = (const float*)d_in[1];  // all_atom_positions   [256,37,3]
    const float* msk  = (const float*)d_in[2];  // all_atom_mask        [256,37]
    float* out = (float*)d_out;
    unsigned long long* ws = (unsigned long long*)d_ws;
    unsigned int* counter = (unsigned int*)(ws + 2 * HSTRIDE);

    // ws is poisoned 0xAA before every timed launch — zero hists + counter.
    hipMemsetAsync(d_ws, 0, (2 * HSTRIDE + 1) * sizeof(unsigned long long), stream);

    saxs_hist_kernel<<<dim3(TPAIRS, 2), dim3(TILE), 0, stream>>>(
        pred, tru, msk, ws, counter, out);
}